// Round 8
// baseline (294.779 us; speedup 1.0000x reference)
//
#include <hip/hip_runtime.h>
#include <cfloat>

#define BB 4
#define LL 2048
#define DMODEL 256
#define DINNER 512
#define DSTATE 16
#define DTRANK 16
#define HID 128
#define NCLS 4
#define CH 32
#define NC 64

typedef unsigned short u16;
typedef __attribute__((ext_vector_type(8))) short bf16x8;
typedef __attribute__((ext_vector_type(4))) float f32x4;

__device__ inline u16 f2b(float v) {
  union { float f; unsigned u; } c; c.f = v;
  unsigned r = c.u + 0x7fffu + ((c.u >> 16) & 1u);
  return (u16)(r >> 16);
}
__device__ inline float b2f(u16 h) {
  union { unsigned u; float f; } c; c.u = ((unsigned)h) << 16;
  return c.f;
}
__device__ inline void atomicMaxF(float* a, float v) {
  if (v >= 0.f) atomicMax((int*)a, __float_as_int(v));
  else atomicMin((unsigned int*)a, __float_as_uint(v));
}

// async global->LDS, 16B per lane (dest = wave-uniform base + lane*16)
#define GLOAD16(gsrc, ldst) \
  __builtin_amdgcn_global_load_lds( \
      (const __attribute__((address_space(1))) unsigned int*)(gsrc), \
      (__attribute__((address_space(3))) unsigned int*)(ldst), 16, 0, 0)

// ------- conv1 fused with im2col: x (B,L,9) -> A' (8192,1152)=[Htaps|Ltaps|Htaps] -------
__global__ __launch_bounds__(256) void k1_conv1A(const float* __restrict__ x,
    const float* __restrict__ w, const float* __restrict__ bias,
    u16* __restrict__ A) {
  int idx = blockIdx.x * 256 + threadIdx.x;  // (b,t,i)
  int i = idx & 127;
  int t = (idx >> 7) & (LL - 1);
  int b = idx >> 18;
  float acc = bias[i];
#pragma unroll
  for (int k = 0; k < 3; ++k) {
    int ts = t + k - 1;
    if (ts < 0 || ts >= LL) continue;
    const float* xr = x + (b * LL + ts) * 9;
    const float* wr = w + i * 27 + k;
#pragma unroll
    for (int c = 0; c < 9; ++c) acc += xr[c] * wr[c * 3];
  }
  float v = fmaxf(acc, 0.f);
  u16 h = f2b(v), l = f2b(v - b2f(h));
#pragma unroll
  for (int tap = 0; tap < 3; ++tap) {
    int rr = t + 1 - tap;              // row rr consumes f1[rr + tap - 1] = f1[t]
    if (rr < 0 || rr >= LL) continue;
    u16* rp = A + ((size_t)(b * LL + rr)) * 1152 + tap * 128 + i;
    rp[0] = h; rp[384] = l; rp[768] = h;
  }
  if (t == 0) {                        // row 0 tap0 has no producer
    u16* rp = A + ((size_t)(b * LL)) * 1152 + i;
    rp[0] = 0; rp[384] = 0; rp[768] = 0;
  }
  if (t == LL - 1) {                   // row 2047 tap2 has no producer
    u16* rp = A + ((size_t)(b * LL + LL - 1)) * 1152 + 256 + i;
    rp[0] = 0; rp[384] = 0; rp[768] = 0;
  }
}

// ------- conv2 weights: (256,128,3) -> (256,1152) = [WHtaps | WHtaps | WLtaps] -------
__global__ __launch_bounds__(256) void k_wconv2_3(const float* __restrict__ w,
    u16* __restrict__ dst) {
  int idx = blockIdx.x * 256 + threadIdx.x;   // o*384 + tap*128 + i
  if (idx >= 256 * 384) return;
  int o = idx / 384, r = idx - o * 384;
  int tap = r >> 7, i = r & 127;
  float v = w[o * 384 + i * 3 + tap];
  u16 h = f2b(v), l = f2b(v - b2f(h));
  u16* rp = dst + (size_t)o * 1152;
  rp[r] = h;
  rp[384 + r] = h;
  rp[768 + r] = l;
}

// ------- generic weights: w (N,K) fp32 -> (N,3K) = [WH | WH | WL]; optional init -------
__global__ __launch_bounds__(256) void k_wsplit3(const float* __restrict__ w,
    u16* __restrict__ dst, int NK, int K, float* initb, int initn) {
  if (initb && blockIdx.x == 0)
    for (int i = threadIdx.x; i < initn; i += 256) initb[i] = -FLT_MAX;
  int idx = blockIdx.x * 256 + threadIdx.x;
  if (idx >= NK) return;
  int n = idx / K, k = idx - n * K;
  float v = w[idx];
  u16 h = f2b(v), l = f2b(v - b2f(h));
  u16* rp = dst + (size_t)n * 3 * K;
  rp[k] = h;
  rp[K + k] = h;
  rp[2 * K + k] = l;
}

// ======= m97-style MFMA GEMM: C[M,N] = A'[M,K'] @ B'[N,K']^T =======
// 128 x TN tile, 4 waves (2x2), BK=64, global_load_lds(16B) staging with
// source-side XOR pre-swizzle + matching XOR on LDS reads, double-buffered,
// bijective XCD blockIdx swizzle.
// EPI 0: fp32 C.  EPI 1: bias+relu, write [H|L|H] split.  EPI 2: max-pool -> atomic.
template <int TN, int EPI, int NBX>
__global__ __launch_bounds__(256) void k_mm(
    const u16* __restrict__ A, const u16* __restrict__ B,
    float* __restrict__ C, const float* __restrict__ bias,
    u16* __restrict__ osp, int N, int K) {
  constexpr int WN = TN / 2;
  constexpr int NB = WN / 16;
  __shared__ u16 As[2][128 * 64];
  __shared__ u16 Bs[2][TN * 64];
  __shared__ float cmw[2][64];
  const int tid = threadIdx.x;
  const int lane = tid & 63;
  const int wid = tid >> 6;
  const int wr = wid >> 1, wc = wid & 1;
  int bid = blockIdx.y * NBX + blockIdx.x;
  int nwg = gridDim.y * NBX;
  int swz = (bid & 7) * (nwg >> 3) + (bid >> 3);
  int bn = swz & (NBX - 1), bm = swz / NBX;
  const int m0 = bm * 128, n0 = bn * TN;
  const int lrow = lane & 15, lg = lane >> 4;
  const int srow = tid >> 3, sg = tid & 7;
  const int NT = K >> 6;

  f32x4 acc[4][NB] = {};

  auto stage = [&](int buf, int k0) {
#pragma unroll
    for (int r = 0; r < 4; ++r) {
      int row = r * 32 + srow;
      const u16* src = A + (size_t)(m0 + row) * K + k0 + ((sg ^ (row & 7)) << 3);
      GLOAD16(src, &As[buf][row * 64 + (sg << 3)]);
    }
#pragma unroll
    for (int r = 0; r < TN / 32; ++r) {
      int row = r * 32 + srow;
      const u16* src = B + (size_t)(n0 + row) * K + k0 + ((sg ^ (row & 7)) << 3);
      GLOAD16(src, &Bs[buf][row * 64 + (sg << 3)]);
    }
  };

  stage(0, 0);
  __syncthreads();
  for (int t = 0; t < NT; ++t) {
    int cur = t & 1;
    if (t + 1 < NT) stage(cur ^ 1, (t + 1) << 6);
#pragma unroll
    for (int kc = 0; kc < 2; ++kc) {
      bf16x8 af[4], bfr[NB];
#pragma unroll
      for (int i = 0; i < 4; ++i) {
        int row = wr * 64 + i * 16 + lrow;
        int g = (kc * 4 + lg) ^ (row & 7);
        af[i] = *(const bf16x8*)&As[cur][row * 64 + (g << 3)];
      }
#pragma unroll
      for (int j = 0; j < NB; ++j) {
        int row = wc * WN + j * 16 + lrow;
        int g = (kc * 4 + lg) ^ (row & 7);
        bfr[j] = *(const bf16x8*)&Bs[cur][row * 64 + (g << 3)];
      }
#pragma unroll
      for (int i = 0; i < 4; ++i)
#pragma unroll
        for (int j = 0; j < NB; ++j)
          acc[i][j] = __builtin_amdgcn_mfma_f32_16x16x32_bf16(af[i], bfr[j], acc[i][j], 0, 0, 0);
    }
    __syncthreads();
  }
  if constexpr (EPI == 2) {
    // per-block column max (128 rows x TN cols) -> atomic into C (=pooled)
    float mj[NB];
#pragma unroll
    for (int j = 0; j < NB; ++j) {
      float m = -FLT_MAX;
#pragma unroll
      for (int i = 0; i < 4; ++i)
#pragma unroll
        for (int r = 0; r < 4; ++r) m = fmaxf(m, acc[i][j][r]);
      m = fmaxf(m, __shfl_xor(m, 16, 64));
      m = fmaxf(m, __shfl_xor(m, 32, 64));
      mj[j] = m;
    }
    if (lane < 16) {
#pragma unroll
      for (int j = 0; j < NB; ++j)
        cmw[wr][wc * WN + j * 16 + lane] = mj[j];
    }
    __syncthreads();
    if (tid < TN) {
      float v = fmaxf(cmw[0][tid], cmw[1][tid]);
      atomicMaxF(&C[(m0 >> 11) * 256 + n0 + tid], v);
    }
  } else {
#pragma unroll
    for (int i = 0; i < 4; ++i)
#pragma unroll
      for (int j = 0; j < NB; ++j)
#pragma unroll
        for (int r = 0; r < 4; ++r) {
          int row = m0 + wr * 64 + i * 16 + lg * 4 + r;
          int col = n0 + wc * WN + j * 16 + lrow;
          if constexpr (EPI == 0) {
            C[(size_t)row * N + col] = acc[i][j][r];
          } else {
            float v = fmaxf(acc[i][j][r] + bias[col], 0.f);
            u16 h = f2b(v), l = f2b(v - b2f(h));
            u16* rp = osp + (size_t)row * 768;
            rp[col] = h;
            rp[256 + col] = l;
            rp[512 + col] = h;
          }
        }
  }
}

// ===== fused dwconv+silu -> x_proj -> dt_proj+softplus =====
// block = 32 rows; u computed per 128-col chunk into LDS (and written to global),
// x_proj dot from LDS, then dt from LDS xb + staged dt_proj_w (stride-17, conflict-free).
__global__ __launch_bounds__(256) void k456(const float* __restrict__ xz,
    const float* __restrict__ dww, const float* __restrict__ dwb,
    const float* __restrict__ xw, const float* __restrict__ dtw,
    const float* __restrict__ dtb, float* __restrict__ u,
    float* __restrict__ xdbl, float* __restrict__ dtO) {
  __shared__ float pool[10320];
  float* As = pool;            // [32][129] during chunk loop
  float* Ws = pool + 4128;     // [48][129] during chunk loop
  int r0 = blockIdx.x * 32;
  int b = r0 >> 11;
  int tid = threadIdx.x;
  int r = tid >> 3, jg = tid & 7;
  float acc[6] = {};
  for (int k0 = 0; k0 < 512; k0 += 128) {
    __syncthreads();
    // compute u tile (32 rows x 128 cols): dwconv + silu
#pragma unroll 4
    for (int ii = 0; ii < 16; ++ii) {
      int e = tid + ii * 256;
      int t = e >> 7, c = e & 127;
      int d = k0 + c;
      int tg = (r0 + t) & (LL - 1);
      float a = dwb[d];
#pragma unroll
      for (int k = 0; k < 4; ++k) {
        int tt = tg - 3 + k;
        if (tt >= 0) a += xz[((size_t)b * LL + tt) * 1024 + d] * dww[d * 4 + k];
      }
      float v = a / (1.f + __expf(-a));
      As[t * 129 + c] = v;
      u[((size_t)b * LL + tg) * 512 + d] = v;
    }
    // stage x_proj_w chunk (48 x 128)
    for (int i = tid; i < 48 * 32; i += 256) {
      int jj = i >> 5, cc = (i & 31) << 2;
      float4 w4 = *(const float4*)(xw + (size_t)jj * 512 + k0 + cc);
      Ws[jj * 129 + cc] = w4.x; Ws[jj * 129 + cc + 1] = w4.y;
      Ws[jj * 129 + cc + 2] = w4.z; Ws[jj * 129 + cc + 3] = w4.w;
    }
    __syncthreads();
    for (int k = 0; k < 128; ++k) {
      float a = As[r * 129 + k];
#pragma unroll
      for (int jj = 0; jj < 6; ++jj)
        acc[jj] += a * Ws[(jg * 6 + jj) * 129 + k];
    }
  }
  __syncthreads();
  // repurpose pool: xb [32][48] + dtwS [512][17]
  float* xb = pool;
  float* dtwS = pool + 1536;
#pragma unroll
  for (int jj = 0; jj < 6; ++jj) {
    int col = jg * 6 + jj;
    xb[r * 48 + col] = acc[jj];
    if (col >= 16) xdbl[(size_t)(r0 + r) * 48 + col] = acc[jj];
  }
  for (int i = tid; i < 8192; i += 256)
    dtwS[(i >> 4) * 17 + (i & 15)] = dtw[i];
  __syncthreads();
  // dt phase: 32x512 elems
  for (int ii = 0; ii < 64; ++ii) {
    int e = tid + ii * 256;
    int t = e >> 9, d = e & 511;
    float a = dtb[d];
#pragma unroll
    for (int q = 0; q < 16; ++q) a += xb[t * 48 + q] * dtwS[d * 17 + q];
    float sp = (a > 20.f) ? a : log1pf(__expf(a));
    dtO[((size_t)b * LL + ((r0 + t) & (LL - 1))) * 512 + d] = sp;
  }
}

// ======== chunked selective scan: 3 passes ========
__global__ __launch_bounds__(512) void k7a_pass1(const float* __restrict__ dt,
    const float* __restrict__ u, const float* __restrict__ xdbl,
    const float* __restrict__ A_log, float* __restrict__ hloc,
    float* __restrict__ dtsum) {
  __shared__ float Bs[CH][16];
  int b = blockIdx.x >> 6;
  int c = blockIdx.x & (NC - 1);
  int d = threadIdx.x;
  {
    int t = threadIdx.x >> 4, s = threadIdx.x & 15;
    Bs[t][s] = xdbl[(b * LL + c * CH + t) * 48 + 16 + s];
  }
  __syncthreads();
  float A_r[16];
#pragma unroll
  for (int s = 0; s < 16; ++s) A_r[s] = -__expf(A_log[d * 16 + s]);
  float h[16];
#pragma unroll
  for (int s = 0; s < 16; ++s) h[s] = 0.f;
  float dsum = 0.f;
  const float* dtp = dt + (size_t)(b * LL + c * CH) * 512 + d;
  const float* up  = u  + (size_t)(b * LL + c * CH) * 512 + d;
  for (int t = 0; t < CH; ++t) {
    float dtv = dtp[t * 512];
    float uv  = up[t * 512];
    float xv = dtv * uv;
    dsum += dtv;
#pragma unroll
    for (int s = 0; s < 16; ++s)
      h[s] = h[s] * __expf(dtv * A_r[s]) + xv * Bs[t][s];
  }
  int base = b * NC + c;
#pragma unroll
  for (int s = 0; s < 16; ++s) hloc[(base * 16 + s) * 512 + d] = h[s];
  dtsum[base * 512 + d] = dsum;
}

__global__ __launch_bounds__(512) void k7b_combine(const float* __restrict__ hloc,
    const float* __restrict__ dtsum, const float* __restrict__ A_log,
    float* __restrict__ h_in) {
  int g = blockIdx.x * 512 + threadIdx.x;
  int d = g & 511;
  int s = (g >> 9) & 15;
  int b = g >> 13;
  float A_r = -__expf(A_log[d * 16 + s]);
  float H = 0.f;
  for (int c = 0; c < NC; ++c) {
    int base = b * NC + c;
    h_in[(base * 16 + s) * 512 + d] = H;
    float P = __expf(A_r * dtsum[base * 512 + d]);
    H = P * H + hloc[(base * 16 + s) * 512 + d];
  }
}

// pass3: replay + gate; writes y2' (8192,1536) = [H | L | H]
__global__ __launch_bounds__(512) void k7c_pass3(const float* __restrict__ dt,
    const float* __restrict__ u, const float* __restrict__ xdbl,
    const float* __restrict__ xz, const float* __restrict__ A_log,
    const float* __restrict__ D_param, const float* __restrict__ h_in,
    u16* __restrict__ y2s) {
  __shared__ float BC[CH][32];
  int b = blockIdx.x >> 6;
  int c = blockIdx.x & (NC - 1);
  int d = threadIdx.x;
  for (int i = threadIdx.x; i < CH * 32; i += 512) {
    int t = i >> 5, j = i & 31;
    BC[t][j] = xdbl[(b * LL + c * CH + t) * 48 + 16 + j];
  }
  __syncthreads();
  float A_r[16];
#pragma unroll
  for (int s = 0; s < 16; ++s) A_r[s] = -__expf(A_log[d * 16 + s]);
  float Dv = D_param[d];
  int base = b * NC + c;
  float h[16];
#pragma unroll
  for (int s = 0; s < 16; ++s) h[s] = h_in[(base * 16 + s) * 512 + d];
  for (int t = 0; t < CH; ++t) {
    int row = b * LL + c * CH + t;
    float dtv = dt[(size_t)row * 512 + d];
    float uv  = u[(size_t)row * 512 + d];
    float xv = dtv * uv;
    float y = 0.f;
#pragma unroll
    for (int s = 0; s < 16; ++s) {
      h[s] = h[s] * __expf(dtv * A_r[s]) + xv * BC[t][s];
      y += h[s] * BC[t][16 + s];
    }
    float zv = xz[(size_t)row * 1024 + 512 + d];
    float sig = 1.f / (1.f + __expf(-zv));
    float v = (y + Dv * uv) * (zv * sig);
    u16 hh = f2b(v);
    u16 ll = f2b(v - b2f(hh));
    u16* rp = y2s + (size_t)row * 1536 + d;
    rp[0] = hh;
    rp[512] = ll;
    rp[1024] = hh;
  }
}

// ---------------- final head: pooled (4,256) -> fc1 relu -> fc2 -> out (4,4) ----------------
__global__ __launch_bounds__(256) void k10_head(const float* __restrict__ pooled,
    const float* __restrict__ fc1_w, const float* __restrict__ fc1_b,
    const float* __restrict__ fc2_w, const float* __restrict__ fc2_b,
    float* __restrict__ out) {
  __shared__ float pl[1024];
  __shared__ float hbuf[4][128];
  int tid = threadIdx.x;
  for (int i = tid; i < 1024; i += 256) pl[i] = pooled[i];
  __syncthreads();
  for (int idx = tid; idx < 512; idx += 256) {
    int b = idx >> 7, i = idx & 127;
    float acc = fc1_b[i];
    for (int o = 0; o < 256; ++o) acc += pl[b * 256 + o] * fc1_w[i * 256 + o];
    hbuf[b][i] = fmaxf(acc, 0.f);
  }
  __syncthreads();
  if (tid < 16) {
    int b = tid >> 2, c = tid & 3;
    float acc = fc2_b[c];
    for (int i = 0; i < 128; ++i) acc += hbuf[b][i] * fc2_w[c * 128 + i];
    out[b * 4 + c] = acc;
  }
}

extern "C" void kernel_launch(void* const* d_in, const int* in_sizes, int n_in,
                              void* d_out, int out_size, void* d_ws, size_t ws_size,
                              hipStream_t stream) {
  (void)in_sizes; (void)n_in; (void)out_size; (void)ws_size;
  const float* x        = (const float*)d_in[0];
  const float* conv1_w  = (const float*)d_in[1];
  const float* conv1_b  = (const float*)d_in[2];
  const float* conv2_w  = (const float*)d_in[3];
  const float* conv2_b  = (const float*)d_in[4];
  const float* in_proj_w= (const float*)d_in[5];
  const float* dw_w     = (const float*)d_in[6];
  const float* dw_b     = (const float*)d_in[7];
  const float* x_proj_w = (const float*)d_in[8];
  const float* dt_proj_w= (const float*)d_in[9];
  const float* dt_proj_b= (const float*)d_in[10];
  const float* A_log    = (const float*)d_in[11];
  const float* D_param  = (const float*)d_in[12];
  const float* out_proj_w=(const float*)d_in[13];
  const float* fc1_w    = (const float*)d_in[14];
  const float* fc1_b    = (const float*)d_in[15];
  const float* fc2_w    = (const float*)d_in[16];
  const float* fc2_b    = (const float*)d_in[17];
  float* out = (float*)d_out;

  float* ws    = (float*)d_ws;
  float* f1A   = ws;                      // 4,718,592 f (8192x1152 u16)
  float* fe    = f1A + 4718592;           // 3,145,728 f (8192x768 u16)
  float* wc2   = fe + 3145728;            //   147,456 f
  float* wi    = wc2 + 147456;            //   393,216 f
  float* wo    = wi + 393216;             //   196,608 f
  float* xz    = wo + 196608;             // 8,388,608 f
  float* u     = xz + 8388608;            // 4,194,304 f
  float* xdbl  = u + 4194304;             //   393,216 f
  float* dt    = xdbl + 393216;           // 4,194,304 f
  float* y2s   = dt + 4194304;            // 6,291,456 f (8192x1536 u16)
  float* pooled= y2s + 6291456;           //     1,024 f
  float* hloc  = pooled + 1024;           // 2,097,152 f
  float* h_in  = hloc + 2097152;          // 2,097,152 f
  float* dts   = h_in + 2097152;          //   131,072 f

  u16* f1Ap = (u16*)f1A;
  u16* fep  = (u16*)fe;
  u16* wc2p = (u16*)wc2;
  u16* wip  = (u16*)wi;
  u16* wop  = (u16*)wo;
  u16* y2p  = (u16*)y2s;

  k1_conv1A<<<dim3(BB * LL * 128 / 256), dim3(256), 0, stream>>>(x, conv1_w, conv1_b, f1Ap);
  k_wconv2_3<<<dim3(384), dim3(256), 0, stream>>>(conv2_w, wc2p);
  // conv2: (8192,1152) x (256,1152)^T -> feat' (bias+relu+split epilogue)
  k_mm<64, 1, 4><<<dim3(4, 64), dim3(256), 0, stream>>>(f1Ap, wc2p, nullptr, conv2_b, fep, 256, 1152);
  k_wsplit3<<<dim3(1024), dim3(256), 0, stream>>>(in_proj_w, wip, 262144, 256, nullptr, 0);
  // in_proj: (8192,768) x (1024,768)^T -> xz fp32
  k_mm<128, 0, 8><<<dim3(8, 64), dim3(256), 0, stream>>>(fep, wip, xz, nullptr, nullptr, 1024, 768);
  // fused dwconv+silu + x_proj + dt
  k456<<<dim3(256), dim3(256), 0, stream>>>(xz, dw_w, dw_b, x_proj_w, dt_proj_w, dt_proj_b, u, xdbl, dt);
  k7a_pass1<<<dim3(BB * NC), dim3(512), 0, stream>>>(dt, u, xdbl, A_log, hloc, dts);
  k7b_combine<<<dim3(BB * 16), dim3(512), 0, stream>>>(hloc, dts, A_log, h_in);
  k7c_pass3<<<dim3(BB * NC), dim3(512), 0, stream>>>(dt, u, xdbl, xz, A_log, D_param, h_in, y2p);
  k_wsplit3<<<dim3(512), dim3(256), 0, stream>>>(out_proj_w, wop, 131072, 512, pooled, 1024);
  // out_proj: (8192,1536) x (256,1536)^T -> fused max-pool into pooled
  k_mm<64, 2, 4><<<dim3(4, 64), dim3(256), 0, stream>>>(y2p, wop, pooled, nullptr, nullptr, 256, 1536);
  k10_head<<<dim3(1), dim3(256), 0, stream>>>(pooled, fc1_w, fc1_b, fc2_w, fc2_b, out);
}

// Round 9
// 260.927 us; speedup vs baseline: 1.1297x; 1.1297x over previous
//
#include <hip/hip_runtime.h>
#include <cfloat>

#define BB 4
#define LL 2048
#define DMODEL 256
#define DINNER 512
#define DSTATE 16
#define DTRANK 16
#define HID 128
#define NCLS 4
#define CH 32
#define NC 64

typedef unsigned short u16;
typedef __attribute__((ext_vector_type(8))) short bf16x8;
typedef __attribute__((ext_vector_type(4))) float f32x4;

__device__ inline u16 f2b(float v) {
  union { float f; unsigned u; } c; c.f = v;
  unsigned r = c.u + 0x7fffu + ((c.u >> 16) & 1u);
  return (u16)(r >> 16);
}
__device__ inline float b2f(u16 h) {
  union { unsigned u; float f; } c; c.u = ((unsigned)h) << 16;
  return c.f;
}
__device__ inline void atomicMaxF(float* a, float v) {
  if (v >= 0.f) atomicMax((int*)a, __float_as_int(v));
  else atomicMin((unsigned int*)a, __float_as_uint(v));
}

// async global->LDS, 16B per lane (dest = wave-uniform base + lane*16)
#define GLOAD16(gsrc, ldst) \
  __builtin_amdgcn_global_load_lds( \
      (const __attribute__((address_space(1))) unsigned int*)(gsrc), \
      (__attribute__((address_space(3))) unsigned int*)(ldst), 16, 0, 0)

// ------- conv1 fused with im2col: x (B,L,9) -> A' (8192,1152)=[Htaps|Ltaps|Htaps] -------
__global__ __launch_bounds__(256) void k1_conv1A(const float* __restrict__ x,
    const float* __restrict__ w, const float* __restrict__ bias,
    u16* __restrict__ A) {
  int idx = blockIdx.x * 256 + threadIdx.x;  // (b,t,i)
  int i = idx & 127;
  int t = (idx >> 7) & (LL - 1);
  int b = idx >> 18;
  float acc = bias[i];
#pragma unroll
  for (int k = 0; k < 3; ++k) {
    int ts = t + k - 1;
    if (ts < 0 || ts >= LL) continue;
    const float* xr = x + (b * LL + ts) * 9;
    const float* wr = w + i * 27 + k;
#pragma unroll
    for (int c = 0; c < 9; ++c) acc += xr[c] * wr[c * 3];
  }
  float v = fmaxf(acc, 0.f);
  u16 h = f2b(v), l = f2b(v - b2f(h));
#pragma unroll
  for (int tap = 0; tap < 3; ++tap) {
    int rr = t + 1 - tap;              // row rr consumes f1[rr + tap - 1] = f1[t]
    if (rr < 0 || rr >= LL) continue;
    u16* rp = A + ((size_t)(b * LL + rr)) * 1152 + tap * 128 + i;
    rp[0] = h; rp[384] = l; rp[768] = h;
  }
  if (t == 0) {
    u16* rp = A + ((size_t)(b * LL)) * 1152 + i;
    rp[0] = 0; rp[384] = 0; rp[768] = 0;
  }
  if (t == LL - 1) {
    u16* rp = A + ((size_t)(b * LL + LL - 1)) * 1152 + 256 + i;
    rp[0] = 0; rp[384] = 0; rp[768] = 0;
  }
}

// ------- conv2 weights: (256,128,3) -> (256,1152) = [WHtaps | WHtaps | WLtaps] -------
__global__ __launch_bounds__(256) void k_wconv2_3(const float* __restrict__ w,
    u16* __restrict__ dst) {
  int idx = blockIdx.x * 256 + threadIdx.x;
  if (idx >= 256 * 384) return;
  int o = idx / 384, r = idx - o * 384;
  int tap = r >> 7, i = r & 127;
  float v = w[o * 384 + i * 3 + tap];
  u16 h = f2b(v), l = f2b(v - b2f(h));
  u16* rp = dst + (size_t)o * 1152;
  rp[r] = h;
  rp[384 + r] = h;
  rp[768 + r] = l;
}

// ------- generic weights: w (N,K) fp32 -> (N,3K) = [WH | WH | WL]; optional init -------
__global__ __launch_bounds__(256) void k_wsplit3(const float* __restrict__ w,
    u16* __restrict__ dst, int NK, int K, float* initb, int initn) {
  if (initb && blockIdx.x == 0)
    for (int i = threadIdx.x; i < initn; i += 256) initb[i] = -FLT_MAX;
  int idx = blockIdx.x * 256 + threadIdx.x;
  if (idx >= NK) return;
  int n = idx / K, k = idx - n * K;
  float v = w[idx];
  u16 h = f2b(v), l = f2b(v - b2f(h));
  u16* rp = dst + (size_t)n * 3 * K;
  rp[k] = h;
  rp[K + k] = h;
  rp[2 * K + k] = l;
}

// ======= m97-style MFMA GEMM: C[M,N] = A'[M,K'] @ B'[N,K']^T =======
// EPI 0: fp32 C.  EPI 1: bias+relu, write [H|L|H] split.  EPI 2: max-pool -> atomic.
template <int TN, int EPI, int NBX>
__global__ __launch_bounds__(256) void k_mm(
    const u16* __restrict__ A, const u16* __restrict__ B,
    float* __restrict__ C, const float* __restrict__ bias,
    u16* __restrict__ osp, int N, int K) {
  constexpr int WN = TN / 2;
  constexpr int NB = WN / 16;
  __shared__ u16 As[2][128 * 64];
  __shared__ u16 Bs[2][TN * 64];
  __shared__ float cmw[2][64];
  const int tid = threadIdx.x;
  const int lane = tid & 63;
  const int wid = tid >> 6;
  const int wr = wid >> 1, wc = wid & 1;
  int bid = blockIdx.y * NBX + blockIdx.x;
  int nwg = gridDim.y * NBX;
  int swz = (bid & 7) * (nwg >> 3) + (bid >> 3);
  int bn = swz & (NBX - 1), bm = swz / NBX;
  const int m0 = bm * 128, n0 = bn * TN;
  const int lrow = lane & 15, lg = lane >> 4;
  const int srow = tid >> 3, sg = tid & 7;
  const int NT = K >> 6;

  f32x4 acc[4][NB] = {};

  auto stage = [&](int buf, int k0) {
#pragma unroll
    for (int r = 0; r < 4; ++r) {
      int row = r * 32 + srow;
      const u16* src = A + (size_t)(m0 + row) * K + k0 + ((sg ^ (row & 7)) << 3);
      GLOAD16(src, &As[buf][row * 64 + (sg << 3)]);
    }
#pragma unroll
    for (int r = 0; r < TN / 32; ++r) {
      int row = r * 32 + srow;
      const u16* src = B + (size_t)(n0 + row) * K + k0 + ((sg ^ (row & 7)) << 3);
      GLOAD16(src, &Bs[buf][row * 64 + (sg << 3)]);
    }
  };

  stage(0, 0);
  __syncthreads();
  for (int t = 0; t < NT; ++t) {
    int cur = t & 1;
    if (t + 1 < NT) stage(cur ^ 1, (t + 1) << 6);
#pragma unroll
    for (int kc = 0; kc < 2; ++kc) {
      bf16x8 af[4], bfr[NB];
#pragma unroll
      for (int i = 0; i < 4; ++i) {
        int row = wr * 64 + i * 16 + lrow;
        int g = (kc * 4 + lg) ^ (row & 7);
        af[i] = *(const bf16x8*)&As[cur][row * 64 + (g << 3)];
      }
#pragma unroll
      for (int j = 0; j < NB; ++j) {
        int row = wc * WN + j * 16 + lrow;
        int g = (kc * 4 + lg) ^ (row & 7);
        bfr[j] = *(const bf16x8*)&Bs[cur][row * 64 + (g << 3)];
      }
#pragma unroll
      for (int i = 0; i < 4; ++i)
#pragma unroll
        for (int j = 0; j < NB; ++j)
          acc[i][j] = __builtin_amdgcn_mfma_f32_16x16x32_bf16(af[i], bfr[j], acc[i][j], 0, 0, 0);
    }
    __syncthreads();
  }
  if constexpr (EPI == 2) {
    float mj[NB];
#pragma unroll
    for (int j = 0; j < NB; ++j) {
      float m = -FLT_MAX;
#pragma unroll
      for (int i = 0; i < 4; ++i)
#pragma unroll
        for (int r = 0; r < 4; ++r) m = fmaxf(m, acc[i][j][r]);
      m = fmaxf(m, __shfl_xor(m, 16, 64));
      m = fmaxf(m, __shfl_xor(m, 32, 64));
      mj[j] = m;
    }
    if (lane < 16) {
#pragma unroll
      for (int j = 0; j < NB; ++j)
        cmw[wr][wc * WN + j * 16 + lane] = mj[j];
    }
    __syncthreads();
    if (tid < TN) {
      float v = fmaxf(cmw[0][tid], cmw[1][tid]);
      atomicMaxF(&C[(m0 >> 11) * 256 + n0 + tid], v);
    }
  } else {
#pragma unroll
    for (int i = 0; i < 4; ++i)
#pragma unroll
      for (int j = 0; j < NB; ++j)
#pragma unroll
        for (int r = 0; r < 4; ++r) {
          int row = m0 + wr * 64 + i * 16 + lg * 4 + r;
          int col = n0 + wc * WN + j * 16 + lrow;
          if constexpr (EPI == 0) {
            C[(size_t)row * N + col] = acc[i][j][r];
          } else {
            float v = fmaxf(acc[i][j][r] + bias[col], 0.f);
            u16 h = f2b(v), l = f2b(v - b2f(h));
            u16* rp = osp + (size_t)row * 768;
            rp[col] = h;
            rp[256 + col] = l;
            rp[512 + col] = h;
          }
        }
  }
}

// ---------------- depthwise causal conv4 + silu: xz -> u (B,L,512) ----------------
__global__ __launch_bounds__(256) void k4_dwconv(const float* __restrict__ xz,
    const float* __restrict__ w, const float* __restrict__ bias,
    float* __restrict__ u) {
  int idx = blockIdx.x * 256 + threadIdx.x;
  int d = idx & 511;
  int t = (idx >> 9) & (LL - 1);
  int b = idx >> 20;
  float acc = bias[d];
#pragma unroll
  for (int k = 0; k < 4; ++k) {
    int tt = t - 3 + k;
    if (tt >= 0) acc += xz[(b * LL + tt) * 1024 + d] * w[d * 4 + k];
  }
  float sig = 1.f / (1.f + __expf(-acc));
  u[idx] = acc * sig;
}

// ---------------- x_proj (LDS-staged): u (8192,512) @ w(48,512)^T -> xdbl ----
__global__ __launch_bounds__(256) void k5_xproj(const float* __restrict__ u,
    const float* __restrict__ w, float* __restrict__ xdbl) {
  __shared__ float As[32][129];
  __shared__ float Ws[48][129];
  int r0 = blockIdx.x * 32;
  int tid = threadIdx.x;
  int r = tid >> 3;
  int jg = tid & 7;
  float acc[6] = {};
  for (int k0 = 0; k0 < 512; k0 += 128) {
    __syncthreads();
    for (int i = tid; i < 32 * 32; i += 256) {
      int rr = i >> 5;
      int cc = (i & 31) << 2;
      float4 v = *(const float4*)(u + (size_t)(r0 + rr) * 512 + k0 + cc);
      As[rr][cc] = v.x; As[rr][cc + 1] = v.y; As[rr][cc + 2] = v.z; As[rr][cc + 3] = v.w;
    }
    for (int i = tid; i < 48 * 32; i += 256) {
      int jj = i >> 5;
      int cc = (i & 31) << 2;
      float4 v = *(const float4*)(w + (size_t)jj * 512 + k0 + cc);
      Ws[jj][cc] = v.x; Ws[jj][cc + 1] = v.y; Ws[jj][cc + 2] = v.z; Ws[jj][cc + 3] = v.w;
    }
    __syncthreads();
    for (int k = 0; k < 128; ++k) {
      float a = As[r][k];
#pragma unroll
      for (int jj = 0; jj < 6; ++jj)
        acc[jj] += a * Ws[jg * 6 + jj][k];
    }
  }
  int row = r0 + r;
#pragma unroll
  for (int jj = 0; jj < 6; ++jj)
    xdbl[(size_t)row * 48 + jg * 6 + jj] = acc[jj];
}

// ---------------- dt: softplus(dt_lr @ dt_proj_w^T + b) -> (8192,512) ----------------
__global__ __launch_bounds__(256) void k6_dt(const float* __restrict__ xdbl,
    const float* __restrict__ w, const float* __restrict__ bias,
    float* __restrict__ dt) {
  int idx = blockIdx.x * 256 + threadIdx.x;
  int d = idx & 511;
  int row = idx >> 9;
  const float* lr = xdbl + row * 48;
  const float* wr = w + d * 16;
  float acc = bias[d];
#pragma unroll
  for (int r = 0; r < 16; ++r) acc += lr[r] * wr[r];
  dt[idx] = (acc > 20.f) ? acc : log1pf(expf(acc));
}

// ======== chunked selective scan: 3 passes ========
__global__ __launch_bounds__(512) void k7a_pass1(const float* __restrict__ dt,
    const float* __restrict__ u, const float* __restrict__ xdbl,
    const float* __restrict__ A_log, float* __restrict__ hloc,
    float* __restrict__ dtsum) {
  __shared__ float Bs[CH][16];
  int b = blockIdx.x >> 6;
  int c = blockIdx.x & (NC - 1);
  int d = threadIdx.x;
  {
    int t = threadIdx.x >> 4, s = threadIdx.x & 15;
    Bs[t][s] = xdbl[(b * LL + c * CH + t) * 48 + 16 + s];
  }
  __syncthreads();
  float A_r[16];
#pragma unroll
  for (int s = 0; s < 16; ++s) A_r[s] = -__expf(A_log[d * 16 + s]);
  float h[16];
#pragma unroll
  for (int s = 0; s < 16; ++s) h[s] = 0.f;
  float dsum = 0.f;
  const float* dtp = dt + (size_t)(b * LL + c * CH) * 512 + d;
  const float* up  = u  + (size_t)(b * LL + c * CH) * 512 + d;
  for (int t = 0; t < CH; ++t) {
    float dtv = dtp[t * 512];
    float uv  = up[t * 512];
    float xv = dtv * uv;
    dsum += dtv;
#pragma unroll
    for (int s = 0; s < 16; ++s)
      h[s] = h[s] * __expf(dtv * A_r[s]) + xv * Bs[t][s];
  }
  int base = b * NC + c;
#pragma unroll
  for (int s = 0; s < 16; ++s) hloc[(base * 16 + s) * 512 + d] = h[s];
  dtsum[base * 512 + d] = dsum;
}

__global__ __launch_bounds__(512) void k7b_combine(const float* __restrict__ hloc,
    const float* __restrict__ dtsum, const float* __restrict__ A_log,
    float* __restrict__ h_in) {
  int g = blockIdx.x * 512 + threadIdx.x;
  int d = g & 511;
  int s = (g >> 9) & 15;
  int b = g >> 13;
  float A_r = -__expf(A_log[d * 16 + s]);
  float H = 0.f;
  for (int c = 0; c < NC; ++c) {
    int base = b * NC + c;
    h_in[(base * 16 + s) * 512 + d] = H;
    float P = __expf(A_r * dtsum[base * 512 + d]);
    H = P * H + hloc[(base * 16 + s) * 512 + d];
  }
}

// pass3: replay + gate; writes y2' (8192,1536) = [H | L | H]
__global__ __launch_bounds__(512) void k7c_pass3(const float* __restrict__ dt,
    const float* __restrict__ u, const float* __restrict__ xdbl,
    const float* __restrict__ xz, const float* __restrict__ A_log,
    const float* __restrict__ D_param, const float* __restrict__ h_in,
    u16* __restrict__ y2s) {
  __shared__ float BC[CH][32];
  int b = blockIdx.x >> 6;
  int c = blockIdx.x & (NC - 1);
  int d = threadIdx.x;
  for (int i = threadIdx.x; i < CH * 32; i += 512) {
    int t = i >> 5, j = i & 31;
    BC[t][j] = xdbl[(b * LL + c * CH + t) * 48 + 16 + j];
  }
  __syncthreads();
  float A_r[16];
#pragma unroll
  for (int s = 0; s < 16; ++s) A_r[s] = -__expf(A_log[d * 16 + s]);
  float Dv = D_param[d];
  int base = b * NC + c;
  float h[16];
#pragma unroll
  for (int s = 0; s < 16; ++s) h[s] = h_in[(base * 16 + s) * 512 + d];
  for (int t = 0; t < CH; ++t) {
    int row = b * LL + c * CH + t;
    float dtv = dt[(size_t)row * 512 + d];
    float uv  = u[(size_t)row * 512 + d];
    float xv = dtv * uv;
    float y = 0.f;
#pragma unroll
    for (int s = 0; s < 16; ++s) {
      h[s] = h[s] * __expf(dtv * A_r[s]) + xv * BC[t][s];
      y += h[s] * BC[t][16 + s];
    }
    float zv = xz[(size_t)row * 1024 + 512 + d];
    float sig = 1.f / (1.f + __expf(-zv));
    float v = (y + Dv * uv) * (zv * sig);
    u16 hh = f2b(v);
    u16 ll = f2b(v - b2f(hh));
    u16* rp = y2s + (size_t)row * 1536 + d;
    rp[0] = hh;
    rp[512] = ll;
    rp[1024] = hh;
  }
}

// ---------------- final head: pooled (4,256) -> fc1 relu -> fc2 -> out (4,4) ----------------
__global__ __launch_bounds__(256) void k10_head(const float* __restrict__ pooled,
    const float* __restrict__ fc1_w, const float* __restrict__ fc1_b,
    const float* __restrict__ fc2_w, const float* __restrict__ fc2_b,
    float* __restrict__ out) {
  __shared__ float pl[1024];
  __shared__ float hbuf[4][128];
  int tid = threadIdx.x;
  for (int i = tid; i < 1024; i += 256) pl[i] = pooled[i];
  __syncthreads();
  for (int idx = tid; idx < 512; idx += 256) {
    int b = idx >> 7, i = idx & 127;
    float acc = fc1_b[i];
    for (int o = 0; o < 256; ++o) acc += pl[b * 256 + o] * fc1_w[i * 256 + o];
    hbuf[b][i] = fmaxf(acc, 0.f);
  }
  __syncthreads();
  if (tid < 16) {
    int b = tid >> 2, c = tid & 3;
    float acc = fc2_b[c];
    for (int i = 0; i < 128; ++i) acc += hbuf[b][i] * fc2_w[c * 128 + i];
    out[b * 4 + c] = acc;
  }
}

extern "C" void kernel_launch(void* const* d_in, const int* in_sizes, int n_in,
                              void* d_out, int out_size, void* d_ws, size_t ws_size,
                              hipStream_t stream) {
  (void)in_sizes; (void)n_in; (void)out_size; (void)ws_size;
  const float* x        = (const float*)d_in[0];
  const float* conv1_w  = (const float*)d_in[1];
  const float* conv1_b  = (const float*)d_in[2];
  const float* conv2_w  = (const float*)d_in[3];
  const float* conv2_b  = (const float*)d_in[4];
  const float* in_proj_w= (const float*)d_in[5];
  const float* dw_w     = (const float*)d_in[6];
  const float* dw_b     = (const float*)d_in[7];
  const float* x_proj_w = (const float*)d_in[8];
  const float* dt_proj_w= (const float*)d_in[9];
  const float* dt_proj_b= (const float*)d_in[10];
  const float* A_log    = (const float*)d_in[11];
  const float* D_param  = (const float*)d_in[12];
  const float* out_proj_w=(const float*)d_in[13];
  const float* fc1_w    = (const float*)d_in[14];
  const float* fc1_b    = (const float*)d_in[15];
  const float* fc2_w    = (const float*)d_in[16];
  const float* fc2_b    = (const float*)d_in[17];
  float* out = (float*)d_out;

  float* ws    = (float*)d_ws;
  float* f1A   = ws;                      // 4,718,592 f (8192x1152 u16)
  float* fe    = f1A + 4718592;           // 3,145,728 f (8192x768 u16)
  float* wc2   = fe + 3145728;            //   147,456 f
  float* wi    = wc2 + 147456;            //   393,216 f
  float* wo    = wi + 393216;             //   196,608 f
  float* xz    = wo + 196608;             // 8,388,608 f
  float* u     = xz + 8388608;            // 4,194,304 f
  float* xdbl  = u + 4194304;             //   393,216 f
  float* dt    = xdbl + 393216;           // 4,194,304 f
  float* y2s   = dt + 4194304;            // 6,291,456 f (8192x1536 u16)
  float* pooled= y2s + 6291456;           //     1,024 f
  float* hloc  = pooled + 1024;           // 2,097,152 f
  float* h_in  = hloc + 2097152;          // 2,097,152 f
  float* dts   = h_in + 2097152;          //   131,072 f

  u16* f1Ap = (u16*)f1A;
  u16* fep  = (u16*)fe;
  u16* wc2p = (u16*)wc2;
  u16* wip  = (u16*)wi;
  u16* wop  = (u16*)wo;
  u16* y2p  = (u16*)y2s;

  k1_conv1A<<<dim3(BB * LL * 128 / 256), dim3(256), 0, stream>>>(x, conv1_w, conv1_b, f1Ap);
  k_wconv2_3<<<dim3(384), dim3(256), 0, stream>>>(conv2_w, wc2p);
  // conv2: (8192,1152) x (256,1152)^T -> feat' (bias+relu+split epilogue)
  k_mm<64, 1, 4><<<dim3(4, 64), dim3(256), 0, stream>>>(f1Ap, wc2p, nullptr, conv2_b, fep, 256, 1152);
  k_wsplit3<<<dim3(1024), dim3(256), 0, stream>>>(in_proj_w, wip, 262144, 256, nullptr, 0);
  // in_proj: (8192,768) x (1024,768)^T -> xz fp32
  k_mm<128, 0, 8><<<dim3(8, 64), dim3(256), 0, stream>>>(fep, wip, xz, nullptr, nullptr, 1024, 768);
  k4_dwconv<<<dim3(BB * LL * 512 / 256), dim3(256), 0, stream>>>(xz, dw_w, dw_b, u);
  k5_xproj<<<dim3(256), dim3(256), 0, stream>>>(u, x_proj_w, xdbl);
  k6_dt<<<dim3(BB * LL * 512 / 256), dim3(256), 0, stream>>>(xdbl, dt_proj_w, dt_proj_b, dt);
  k7a_pass1<<<dim3(BB * NC), dim3(512), 0, stream>>>(dt, u, xdbl, A_log, hloc, dts);
  k7b_combine<<<dim3(BB * 16), dim3(512), 0, stream>>>(hloc, dts, A_log, h_in);
  k7c_pass3<<<dim3(BB * NC), dim3(512), 0, stream>>>(dt, u, xdbl, xz, A_log, D_param, h_in, y2p);
  k_wsplit3<<<dim3(512), dim3(256), 0, stream>>>(out_proj_w, wop, 131072, 512, pooled, 1024);
  // out_proj: (8192,1536) x (256,1536)^T -> fused max-pool into pooled
  k_mm<64, 2, 4><<<dim3(4, 64), dim3(256), 0, stream>>>(y2p, wop, pooled, nullptr, nullptr, 256, 1536);
  k10_head<<<dim3(1), dim3(256), 0, stream>>>(pooled, fc1_w, fc1_b, fc2_w, fc2_b, out);
}

// Round 10
// 240.834 us; speedup vs baseline: 1.2240x; 1.0834x over previous
//
#include <hip/hip_runtime.h>
#include <cfloat>

#define BB 4
#define LL 2048
#define DSTATE 16
#define CH 32
#define NC 64

typedef unsigned short u16;
typedef __attribute__((ext_vector_type(8))) short bf16x8;
typedef __attribute__((ext_vector_type(4))) float f32x4;

__device__ inline u16 f2b(float v) {
  union { float f; unsigned u; } c; c.f = v;
  unsigned r = c.u + 0x7fffu + ((c.u >> 16) & 1u);
  return (u16)(r >> 16);
}
__device__ inline float b2f(u16 h) {
  union { unsigned u; float f; } c; c.u = ((unsigned)h) << 16;
  return c.f;
}
__device__ inline void atomicMaxF(float* a, float v) {
  if (v >= 0.f) atomicMax((int*)a, __float_as_int(v));
  else atomicMin((unsigned int*)a, __float_as_uint(v));
}

#define GLOAD16(gsrc, ldst) \
  __builtin_amdgcn_global_load_lds( \
      (const __attribute__((address_space(1))) unsigned int*)(gsrc), \
      (__attribute__((address_space(3))) unsigned int*)(ldst), 16, 0, 0)

// ------- conv1 fused with im2col: x (B,L,9) -> A' (8192,1152)=[Htaps|Ltaps|Htaps] -------
__global__ __launch_bounds__(256) void k1_conv1A(const float* __restrict__ x,
    const float* __restrict__ w, const float* __restrict__ bias,
    u16* __restrict__ A) {
  int idx = blockIdx.x * 256 + threadIdx.x;  // (b,t,i)
  int i = idx & 127;
  int t = (idx >> 7) & (LL - 1);
  int b = idx >> 18;
  float acc = bias[i];
#pragma unroll
  for (int k = 0; k < 3; ++k) {
    int ts = t + k - 1;
    if (ts < 0 || ts >= LL) continue;
    const float* xr = x + (b * LL + ts) * 9;
    const float* wr = w + i * 27 + k;
#pragma unroll
    for (int c = 0; c < 9; ++c) acc += xr[c] * wr[c * 3];
  }
  float v = fmaxf(acc, 0.f);
  u16 h = f2b(v), l = f2b(v - b2f(h));
#pragma unroll
  for (int tap = 0; tap < 3; ++tap) {
    int rr = t + 1 - tap;
    if (rr < 0 || rr >= LL) continue;
    u16* rp = A + ((size_t)(b * LL + rr)) * 1152 + tap * 128 + i;
    rp[0] = h; rp[384] = l; rp[768] = h;
  }
  if (t == 0) {
    u16* rp = A + ((size_t)(b * LL)) * 1152 + i;
    rp[0] = 0; rp[384] = 0; rp[768] = 0;
  }
  if (t == LL - 1) {
    u16* rp = A + ((size_t)(b * LL + LL - 1)) * 1152 + 256 + i;
    rp[0] = 0; rp[384] = 0; rp[768] = 0;
  }
}

// ------- ALL weight prep in one kernel (conv2 W', in_proj W', out_proj W', pooled init) ----
__global__ __launch_bounds__(256) void k_prep(const float* __restrict__ wc2,
    const float* __restrict__ wip, const float* __restrict__ wop,
    u16* __restrict__ dc2, u16* __restrict__ dip, u16* __restrict__ dop,
    float* __restrict__ pooled) {
  int idx = blockIdx.x * 256 + threadIdx.x;
  if (idx < 98304) {                        // conv2: (256,128,3) -> [WH|WH|WL] taps
    int o = idx / 384, r2 = idx - o * 384;
    int tap = r2 >> 7, i = r2 & 127;
    float v = wc2[o * 384 + i * 3 + tap];
    u16 h = f2b(v), l = f2b(v - b2f(h));
    u16* rp = dc2 + (size_t)o * 1152;
    rp[r2] = h; rp[384 + r2] = h; rp[768 + r2] = l;
  } else if (idx < 98304 + 262144) {        // in_proj (1024,256) -> [WH|WH|WL]
    int j = idx - 98304;
    int n = j >> 8, k = j & 255;
    float v = wip[j];
    u16 h = f2b(v), l = f2b(v - b2f(h));
    u16* rp = dip + (size_t)n * 768;
    rp[k] = h; rp[256 + k] = h; rp[512 + k] = l;
  } else if (idx < 98304 + 262144 + 131072) {  // out_proj (256,512) -> [WH|WH|WL]
    int j = idx - 98304 - 262144;
    int n = j >> 9, k = j & 511;
    float v = wop[j];
    u16 h = f2b(v), l = f2b(v - b2f(h));
    u16* rp = dop + (size_t)n * 1536;
    rp[k] = h; rp[512 + k] = h; rp[1024 + k] = l;
  } else if (idx < 98304 + 262144 + 131072 + 1024) {
    pooled[idx - 491520] = -FLT_MAX;
  }
}

// ======= m97-style MFMA GEMM: C[M,N] = A'[M,K'] @ B'[N,K']^T =======
// TM x TN tile, 4 waves (2x2), BK=64, global_load_lds(16B) staging with
// source-side XOR pre-swizzle + matching XOR on reads, double-buffered,
// bijective XCD swizzle. EPI 0: fp32 C. EPI 1: bias+relu+[H|L|H]. EPI 2: max-pool atomic.
template <int TM, int TN, int EPI, int NBX>
__global__ __launch_bounds__(256) void k_mm(
    const u16* __restrict__ A, const u16* __restrict__ B,
    float* __restrict__ C, const float* __restrict__ bias,
    u16* __restrict__ osp, int N, int K) {
  constexpr int WM = TM / 2, WN = TN / 2;
  constexpr int NA = WM / 16, NB = WN / 16;
  __shared__ u16 As[2][TM * 64];
  __shared__ u16 Bs[2][TN * 64];
  __shared__ float cmw[2][TN];
  const int tid = threadIdx.x;
  const int lane = tid & 63;
  const int wid = tid >> 6;
  const int wr = wid >> 1, wc = wid & 1;
  int bid = blockIdx.y * NBX + blockIdx.x;
  int nwg = gridDim.y * NBX;
  int swz = (bid & 7) * (nwg >> 3) + (bid >> 3);
  int bn = swz & (NBX - 1), bm = swz / NBX;
  const int m0 = bm * TM, n0 = bn * TN;
  const int lrow = lane & 15, lg = lane >> 4;
  const int srow = tid >> 3, sg = tid & 7;
  const int NT = K >> 6;

  f32x4 acc[NA][NB] = {};

  auto stage = [&](int buf, int k0) {
#pragma unroll
    for (int r = 0; r < TM / 32; ++r) {
      int row = r * 32 + srow;
      const u16* src = A + (size_t)(m0 + row) * K + k0 + ((sg ^ (row & 7)) << 3);
      GLOAD16(src, &As[buf][row * 64 + (sg << 3)]);
    }
#pragma unroll
    for (int r = 0; r < TN / 32; ++r) {
      int row = r * 32 + srow;
      const u16* src = B + (size_t)(n0 + row) * K + k0 + ((sg ^ (row & 7)) << 3);
      GLOAD16(src, &Bs[buf][row * 64 + (sg << 3)]);
    }
  };

  stage(0, 0);
  __syncthreads();
  for (int t = 0; t < NT; ++t) {
    int cur = t & 1;
    if (t + 1 < NT) stage(cur ^ 1, (t + 1) << 6);
#pragma unroll
    for (int kc = 0; kc < 2; ++kc) {
      bf16x8 af[NA], bfr[NB];
#pragma unroll
      for (int i = 0; i < NA; ++i) {
        int row = wr * WM + i * 16 + lrow;
        int g = (kc * 4 + lg) ^ (row & 7);
        af[i] = *(const bf16x8*)&As[cur][row * 64 + (g << 3)];
      }
#pragma unroll
      for (int j = 0; j < NB; ++j) {
        int row = wc * WN + j * 16 + lrow;
        int g = (kc * 4 + lg) ^ (row & 7);
        bfr[j] = *(const bf16x8*)&Bs[cur][row * 64 + (g << 3)];
      }
#pragma unroll
      for (int i = 0; i < NA; ++i)
#pragma unroll
        for (int j = 0; j < NB; ++j)
          acc[i][j] = __builtin_amdgcn_mfma_f32_16x16x32_bf16(af[i], bfr[j], acc[i][j], 0, 0, 0);
    }
    __syncthreads();
  }
  if constexpr (EPI == 2) {
    float mj[NB];
#pragma unroll
    for (int j = 0; j < NB; ++j) {
      float m = -FLT_MAX;
#pragma unroll
      for (int i = 0; i < NA; ++i)
#pragma unroll
        for (int r = 0; r < 4; ++r) m = fmaxf(m, acc[i][j][r]);
      m = fmaxf(m, __shfl_xor(m, 16, 64));
      m = fmaxf(m, __shfl_xor(m, 32, 64));
      mj[j] = m;
    }
    if (lane < 16) {
#pragma unroll
      for (int j = 0; j < NB; ++j)
        cmw[wr][wc * WN + j * 16 + lane] = mj[j];
    }
    __syncthreads();
    if (tid < TN) {
      float v = fmaxf(cmw[0][tid], cmw[1][tid]);
      atomicMaxF(&C[(m0 >> 11) * 256 + n0 + tid], v);
    }
  } else {
#pragma unroll
    for (int i = 0; i < NA; ++i)
#pragma unroll
      for (int j = 0; j < NB; ++j)
#pragma unroll
        for (int r = 0; r < 4; ++r) {
          int row = m0 + wr * WM + i * 16 + lg * 4 + r;
          int col = n0 + wc * WN + j * 16 + lrow;
          if constexpr (EPI == 0) {
            C[(size_t)row * N + col] = acc[i][j][r];
          } else {
            float v = fmaxf(acc[i][j][r] + bias[col], 0.f);
            u16 h = f2b(v), l = f2b(v - b2f(h));
            u16* rp = osp + (size_t)row * 768;
            rp[col] = h;
            rp[256 + col] = l;
            rp[512 + col] = h;
          }
        }
  }
}

// ---------------- depthwise causal conv4 + silu: xz -> u (B,L,512) ----------------
__global__ __launch_bounds__(256) void k4_dwconv(const float* __restrict__ xz,
    const float* __restrict__ w, const float* __restrict__ bias,
    float* __restrict__ u) {
  int idx = blockIdx.x * 256 + threadIdx.x;
  int d = idx & 511;
  int t = (idx >> 9) & (LL - 1);
  int b = idx >> 20;
  float acc = bias[d];
#pragma unroll
  for (int k = 0; k < 4; ++k) {
    int tt = t - 3 + k;
    if (tt >= 0) acc += xz[(b * LL + tt) * 1024 + d] * w[d * 4 + k];
  }
  float sig = 1.f / (1.f + __expf(-acc));
  u[idx] = acc * sig;
}

// ===== fused x_proj + dt (16 rows/block, 512 blocks, ~2 blocks/CU) =====
__global__ __launch_bounds__(256) void k56(const float* __restrict__ u,
    const float* __restrict__ xw, const float* __restrict__ dtw,
    const float* __restrict__ dtb, float* __restrict__ xdbl,
    float* __restrict__ dtO) {
  __shared__ float pool[9472];
  float* As = pool;            // [16][129]
  float* Ws = pool + 2064;     // [48][129]
  int r0 = blockIdx.x * 16;
  int tid = threadIdx.x;
  int r = tid >> 4, jg = tid & 15;   // 16 rows x 16 col-groups (3 cols each)
  float acc[3] = {};
  for (int k0 = 0; k0 < 512; k0 += 128) {
    __syncthreads();
    for (int i = tid; i < 512; i += 256) {          // u tile 16x128
      int rr = i >> 5, cc = (i & 31) << 2;
      float4 v = *(const float4*)(u + (size_t)(r0 + rr) * 512 + k0 + cc);
      As[rr * 129 + cc] = v.x; As[rr * 129 + cc + 1] = v.y;
      As[rr * 129 + cc + 2] = v.z; As[rr * 129 + cc + 3] = v.w;
    }
    for (int i = tid; i < 1536; i += 256) {         // W tile 48x128
      int jj = i >> 5, cc = (i & 31) << 2;
      float4 v = *(const float4*)(xw + (size_t)jj * 512 + k0 + cc);
      Ws[jj * 129 + cc] = v.x; Ws[jj * 129 + cc + 1] = v.y;
      Ws[jj * 129 + cc + 2] = v.z; Ws[jj * 129 + cc + 3] = v.w;
    }
    __syncthreads();
    for (int k = 0; k < 128; ++k) {
      float a = As[r * 129 + k];
#pragma unroll
      for (int jj = 0; jj < 3; ++jj)
        acc[jj] += a * Ws[(jg * 3 + jj) * 129 + k];
    }
  }
  __syncthreads();
  float* xb = pool;            // [16][48]
  float* dtwS = pool + 768;    // [512][17]
#pragma unroll
  for (int jj = 0; jj < 3; ++jj) {
    int col = jg * 3 + jj;
    xb[r * 48 + col] = acc[jj];
    if (col >= 16) xdbl[(size_t)(r0 + r) * 48 + col] = acc[jj];
  }
  for (int i = tid; i < 8192; i += 256)
    dtwS[(i >> 4) * 17 + (i & 15)] = dtw[i];
  __syncthreads();
  for (int ii = 0; ii < 32; ++ii) {
    int e = tid + ii * 256;
    int t = e >> 9, d = e & 511;
    float a = dtb[d];
#pragma unroll
    for (int q = 0; q < 16; ++q) a += xb[t * 48 + q] * dtwS[d * 17 + q];
    dtO[(size_t)(r0 + t) * 512 + d] = (a > 20.f) ? a : log1pf(__expf(a));
  }
}

// ======== chunked selective scan: 3 passes ========
__global__ __launch_bounds__(512) void k7a_pass1(const float* __restrict__ dt,
    const float* __restrict__ u, const float* __restrict__ xdbl,
    const float* __restrict__ A_log, float* __restrict__ hloc,
    float* __restrict__ dtsum) {
  __shared__ float Bs[CH][16];
  int b = blockIdx.x >> 6;
  int c = blockIdx.x & (NC - 1);
  int d = threadIdx.x;
  {
    int t = threadIdx.x >> 4, s = threadIdx.x & 15;
    Bs[t][s] = xdbl[(b * LL + c * CH + t) * 48 + 16 + s];
  }
  __syncthreads();
  float A_r[16];
#pragma unroll
  for (int s = 0; s < 16; ++s) A_r[s] = -__expf(A_log[d * 16 + s]);
  float h[16];
#pragma unroll
  for (int s = 0; s < 16; ++s) h[s] = 0.f;
  float dsum = 0.f;
  const float* dtp = dt + (size_t)(b * LL + c * CH) * 512 + d;
  const float* up  = u  + (size_t)(b * LL + c * CH) * 512 + d;
  for (int t = 0; t < CH; ++t) {
    float dtv = dtp[t * 512];
    float uv  = up[t * 512];
    float xv = dtv * uv;
    dsum += dtv;
#pragma unroll
    for (int s = 0; s < 16; ++s)
      h[s] = h[s] * __expf(dtv * A_r[s]) + xv * Bs[t][s];
  }
  int base = b * NC + c;
#pragma unroll
  for (int s = 0; s < 16; ++s) hloc[(base * 16 + s) * 512 + d] = h[s];
  dtsum[base * 512 + d] = dsum;
}

__global__ __launch_bounds__(512) void k7b_combine(const float* __restrict__ hloc,
    const float* __restrict__ dtsum, const float* __restrict__ A_log,
    float* __restrict__ h_in) {
  int g = blockIdx.x * 512 + threadIdx.x;
  int d = g & 511;
  int s = (g >> 9) & 15;
  int b = g >> 13;
  float A_r = -__expf(A_log[d * 16 + s]);
  float H = 0.f;
  for (int c = 0; c < NC; ++c) {
    int base = b * NC + c;
    h_in[(base * 16 + s) * 512 + d] = H;
    float P = __expf(A_r * dtsum[base * 512 + d]);
    H = P * H + hloc[(base * 16 + s) * 512 + d];
  }
}

// pass3: replay + gate; writes y2' (8192,1536) = [H | L | H]
__global__ __launch_bounds__(512) void k7c_pass3(const float* __restrict__ dt,
    const float* __restrict__ u, const float* __restrict__ xdbl,
    const float* __restrict__ xz, const float* __restrict__ A_log,
    const float* __restrict__ D_param, const float* __restrict__ h_in,
    u16* __restrict__ y2s) {
  __shared__ float BC[CH][32];
  int b = blockIdx.x >> 6;
  int c = blockIdx.x & (NC - 1);
  int d = threadIdx.x;
  for (int i = threadIdx.x; i < CH * 32; i += 512) {
    int t = i >> 5, j = i & 31;
    BC[t][j] = xdbl[(b * LL + c * CH + t) * 48 + 16 + j];
  }
  __syncthreads();
  float A_r[16];
#pragma unroll
  for (int s = 0; s < 16; ++s) A_r[s] = -__expf(A_log[d * 16 + s]);
  float Dv = D_param[d];
  int base = b * NC + c;
  float h[16];
#pragma unroll
  for (int s = 0; s < 16; ++s) h[s] = h_in[(base * 16 + s) * 512 + d];
  for (int t = 0; t < CH; ++t) {
    int row = b * LL + c * CH + t;
    float dtv = dt[(size_t)row * 512 + d];
    float uv  = u[(size_t)row * 512 + d];
    float xv = dtv * uv;
    float y = 0.f;
#pragma unroll
    for (int s = 0; s < 16; ++s) {
      h[s] = h[s] * __expf(dtv * A_r[s]) + xv * BC[t][s];
      y += h[s] * BC[t][16 + s];
    }
    float zv = xz[(size_t)row * 1024 + 512 + d];
    float sig = 1.f / (1.f + __expf(-zv));
    float v = (y + Dv * uv) * (zv * sig);
    u16 hh = f2b(v);
    u16 ll = f2b(v - b2f(hh));
    u16* rp = y2s + (size_t)row * 1536 + d;
    rp[0] = hh;
    rp[512] = ll;
    rp[1024] = hh;
  }
}

// ---------------- final head ----------------
__global__ __launch_bounds__(256) void k10_head(const float* __restrict__ pooled,
    const float* __restrict__ fc1_w, const float* __restrict__ fc1_b,
    const float* __restrict__ fc2_w, const float* __restrict__ fc2_b,
    float* __restrict__ out) {
  __shared__ float pl[1024];
  __shared__ float hbuf[4][128];
  int tid = threadIdx.x;
  for (int i = tid; i < 1024; i += 256) pl[i] = pooled[i];
  __syncthreads();
  for (int idx = tid; idx < 512; idx += 256) {
    int b = idx >> 7, i = idx & 127;
    float acc = fc1_b[i];
    for (int o = 0; o < 256; ++o) acc += pl[b * 256 + o] * fc1_w[i * 256 + o];
    hbuf[b][i] = fmaxf(acc, 0.f);
  }
  __syncthreads();
  if (tid < 16) {
    int b = tid >> 2, c = tid & 3;
    float acc = fc2_b[c];
    for (int i = 0; i < 128; ++i) acc += hbuf[b][i] * fc2_w[c * 128 + i];
    out[b * 4 + c] = acc;
  }
}

extern "C" void kernel_launch(void* const* d_in, const int* in_sizes, int n_in,
                              void* d_out, int out_size, void* d_ws, size_t ws_size,
                              hipStream_t stream) {
  (void)in_sizes; (void)n_in; (void)out_size; (void)ws_size;
  const float* x        = (const float*)d_in[0];
  const float* conv1_w  = (const float*)d_in[1];
  const float* conv1_b  = (const float*)d_in[2];
  const float* conv2_w  = (const float*)d_in[3];
  const float* conv2_b  = (const float*)d_in[4];
  const float* in_proj_w= (const float*)d_in[5];
  const float* dw_w     = (const float*)d_in[6];
  const float* dw_b     = (const float*)d_in[7];
  const float* x_proj_w = (const float*)d_in[8];
  const float* dt_proj_w= (const float*)d_in[9];
  const float* dt_proj_b= (const float*)d_in[10];
  const float* A_log    = (const float*)d_in[11];
  const float* D_param  = (const float*)d_in[12];
  const float* out_proj_w=(const float*)d_in[13];
  const float* fc1_w    = (const float*)d_in[14];
  const float* fc1_b    = (const float*)d_in[15];
  const float* fc2_w    = (const float*)d_in[16];
  const float* fc2_b    = (const float*)d_in[17];
  float* out = (float*)d_out;

  float* ws    = (float*)d_ws;
  float* f1A   = ws;                      // 4,718,592 f (8192x1152 u16)
  float* fe    = f1A + 4718592;           // 3,145,728 f (8192x768 u16)
  float* wc2   = fe + 3145728;            //   147,456 f
  float* wi    = wc2 + 147456;            //   393,216 f
  float* wo    = wi + 393216;             //   196,608 f
  float* xz    = wo + 196608;             // 8,388,608 f
  float* u     = xz + 8388608;            // 4,194,304 f
  float* xdbl  = u + 4194304;             //   393,216 f
  float* dt    = xdbl + 393216;           // 4,194,304 f
  float* y2s   = dt + 4194304;            // 6,291,456 f (8192x1536 u16)
  float* pooled= y2s + 6291456;           //     1,024 f
  float* hloc  = pooled + 1024;           // 2,097,152 f
  float* h_in  = hloc + 2097152;          // 2,097,152 f
  float* dts   = h_in + 2097152;          //   131,072 f

  u16* f1Ap = (u16*)f1A;
  u16* fep  = (u16*)fe;
  u16* wc2p = (u16*)wc2;
  u16* wip  = (u16*)wi;
  u16* wop  = (u16*)wo;
  u16* y2p  = (u16*)y2s;

  k1_conv1A<<<dim3(BB * LL * 128 / 256), dim3(256), 0, stream>>>(x, conv1_w, conv1_b, f1Ap);
  k_prep<<<dim3(1924), dim3(256), 0, stream>>>(conv2_w, in_proj_w, out_proj_w, wc2p, wip, wop, pooled);
  // conv2: (8192,1152) x (256,1152)^T, 64x64 tiles -> 512 blocks
  k_mm<64, 64, 1, 4><<<dim3(4, 128), dim3(256), 0, stream>>>(f1Ap, wc2p, nullptr, conv2_b, fep, 256, 1152);
  // in_proj: (8192,768) x (1024,768)^T, 128x128 tiles -> 512 blocks
  k_mm<128, 128, 0, 8><<<dim3(8, 64), dim3(256), 0, stream>>>(fep, wip, xz, nullptr, nullptr, 1024, 768);
  k4_dwconv<<<dim3(BB * LL * 512 / 256), dim3(256), 0, stream>>>(xz, dw_w, dw_b, u);
  // fused x_proj + dt
  k56<<<dim3(512), dim3(256), 0, stream>>>(u, x_proj_w, dt_proj_w, dt_proj_b, xdbl, dt);
  k7a_pass1<<<dim3(BB * NC), dim3(512), 0, stream>>>(dt, u, xdbl, A_log, hloc, dts);
  k7b_combine<<<dim3(BB * 16), dim3(512), 0, stream>>>(hloc, dts, A_log, h_in);
  k7c_pass3<<<dim3(BB * NC), dim3(512), 0, stream>>>(dt, u, xdbl, xz, A_log, D_param, h_in, y2p);
  // out_proj: (8192,1536) x (256,1536)^T, 64x64 tiles -> 512 blocks, fused max-pool
  k_mm<64, 64, 2, 4><<<dim3(4, 128), dim3(256), 0, stream>>>(y2p, wop, pooled, nullptr, nullptr, 256, 1536);
  k10_head<<<dim3(1), dim3(256), 0, stream>>>(pooled, fc1_w, fc1_b, fc2_w, fc2_b, out);
}